// Round 1
// baseline (226.347 us; speedup 1.0000x reference)
//
#include <hip/hip_runtime.h>
#include <hip/hip_bf16.h>

// LowRankAttention: kv = x @ Wkv^T ; S = routers @ kv^T * scale ; P = softmax(S)
// ; AO = P @ kv ; out = AO @ Wproj^T + bias.  All GEMMs bf16 MFMA (f32 accum).
// Shapes: bs=32 ns=512 seq=1024 H=8 d_r=64 d_model=256.

typedef __attribute__((ext_vector_type(8))) short short8;
typedef __attribute__((ext_vector_type(4))) short short4v;
typedef __attribute__((ext_vector_type(4))) float f32x4;
typedef __attribute__((ext_vector_type(4))) unsigned int uint4v;
typedef __attribute__((ext_vector_type(4))) unsigned short ushort4v;

__device__ inline unsigned short f2bf(float f) {
  unsigned int u = __float_as_uint(f);
  u += 0x7FFFu + ((u >> 16) & 1u);   // RNE
  return (unsigned short)(u >> 16);
}

__global__ __launch_bounds__(256) void cast_f32_bf16(const float* __restrict__ in,
                                                     unsigned short* __restrict__ out, int n4) {
  int i = blockIdx.x * 256 + threadIdx.x;
  if (i >= n4) return;
  float4 v = ((const float4*)in)[i];
  ushort4v w; w.x = f2bf(v.x); w.y = f2bf(v.y); w.z = f2bf(v.z); w.w = f2bf(v.w);
  ((ushort4v*)out)[i] = w;
}

// C[m,n] = sum_k A[m,k] * B[n,k]   (bt layout; TRANS_B: B is K-major (k rows, n cols))
// Batched via blockIdx.y: batch -> (bo=batch/binner, bi=batch%binner), element offsets
// bo*str?o + bi*str?i for A/B/C.
template<int BM,int BN,int BK,int WM,int WN,bool TRANS_B,bool A_F32,bool OUT_BF16,bool DO_SCALE,bool DO_BIAS>
__global__ __launch_bounds__(256) void gemm_bt(
    const void* __restrict__ Av, const unsigned short* __restrict__ Bp,
    void* __restrict__ Cv, const float* __restrict__ bias,
    int lda, int ldb, int ldc, int K, int nWGn,
    long long strAo, long long strAi, long long strBo, long long strBi,
    long long strCo, long long strCi, int binner, float scale)
{
  constexpr int PADA = 8;
  constexpr int PADB = TRANS_B ? 4 : 8;   // PAD=4: transposed scalar writes land 16 banks apart; b64-aligned reads
  constexpr int STRA = BK + PADA;
  constexpr int STRB = BK + PADB;
  constexpr int NWN = BN / WN;
  constexpr int MF = WM / 16, NF = WN / 16;
  __shared__ __align__(16) unsigned short lds_a[BM * STRA];
  __shared__ __align__(16) unsigned short lds_b[BN * STRB];

  const int tid = threadIdx.x;
  const int bn = blockIdx.x % nWGn;
  const int bm = blockIdx.x / nWGn;
  const int batch = blockIdx.y;
  const int bo = batch / binner, bi = batch % binner;

  const int wave = tid >> 6, lane = tid & 63;
  const int wm = wave / NWN, wn = wave % NWN;
  const int lr = lane & 15;           // A row / B col / C col within 16
  const int lk = (lane >> 4) * 8;     // k offset within 32

  const long long abase = bo*strAo + bi*strAi + (long long)bm*BM*lda;
  const long long bbase = bo*strBo + bi*strBi;

  f32x4 acc[MF][NF];
  #pragma unroll
  for (int mi = 0; mi < MF; ++mi)
    #pragma unroll
    for (int ni = 0; ni < NF; ++ni)
      acc[mi][ni] = f32x4{0.f, 0.f, 0.f, 0.f};

  for (int k0 = 0; k0 < K; k0 += BK) {
    // ---- stage A tile (BM x BK) ----
    if constexpr (A_F32) {
      const float* Af = (const float*)Av + abase + k0;
      #pragma unroll
      for (int i = 0; i < BM*BK/1024; ++i) {         // 4 f32 per thread per iter
        int c = i*256 + tid;
        int r = c / (BK/4);
        int kc = (c % (BK/4)) * 4;
        float4 v = *(const float4*)(Af + (long long)r*lda + kc);
        ushort4v w; w.x=f2bf(v.x); w.y=f2bf(v.y); w.z=f2bf(v.z); w.w=f2bf(v.w);
        *(ushort4v*)&lds_a[r*STRA + kc] = w;
      }
    } else {
      const unsigned short* Ab = (const unsigned short*)Av + abase + k0;
      #pragma unroll
      for (int i = 0; i < BM*BK/2048; ++i) {         // 8 bf16 per thread per iter
        int c = i*256 + tid;
        int r = c / (BK/8);
        int kc = (c % (BK/8)) * 8;
        *(uint4v*)&lds_a[r*STRA + kc] = *(const uint4v*)(Ab + (long long)r*lda + kc);
      }
    }
    // ---- stage B tile ----
    if constexpr (!TRANS_B) {
      const unsigned short* Bb = Bp + bbase + (long long)bn*BN*ldb + k0;
      #pragma unroll
      for (int i = 0; i < BN*BK/2048; ++i) {
        int c = i*256 + tid;
        int r = c / (BK/8);
        int kc = (c % (BK/8)) * 8;
        *(uint4v*)&lds_b[r*STRB + kc] = *(const uint4v*)(Bb + (long long)r*ldb + kc);
      }
    } else {
      // B global rows are k (ldb stride), cols n; transpose into lds_b[n][k]
      const unsigned short* Bb = Bp + bbase + (long long)k0*ldb + (long long)bn*BN;
      #pragma unroll
      for (int i = 0; i < BN*BK/2048; ++i) {
        int c = i*256 + tid;
        int kr = c / (BN/8);
        int nc = (c % (BN/8)) * 8;
        uint4v v = *(const uint4v*)(Bb + (long long)kr*ldb + nc);
        const unsigned short* pv = (const unsigned short*)&v;
        #pragma unroll
        for (int j = 0; j < 8; ++j) lds_b[(nc+j)*STRB + kr] = pv[j];
      }
    }
    __syncthreads();

    #pragma unroll
    for (int kk = 0; kk < BK/32; ++kk) {
      short8 af[MF]; short8 bfr[NF];
      #pragma unroll
      for (int mi = 0; mi < MF; ++mi)
        af[mi] = *(const short8*)&lds_a[(wm*WM + mi*16 + lr)*STRA + kk*32 + lk];
      #pragma unroll
      for (int ni = 0; ni < NF; ++ni) {
        if constexpr (TRANS_B) {
          int base = (wn*WN + ni*16 + lr)*STRB + kk*32 + lk;
          short4v lo = *(const short4v*)&lds_b[base];
          short4v hi = *(const short4v*)&lds_b[base + 4];
          short8 t; t[0]=lo[0]; t[1]=lo[1]; t[2]=lo[2]; t[3]=lo[3];
                    t[4]=hi[0]; t[5]=hi[1]; t[6]=hi[2]; t[7]=hi[3];
          bfr[ni] = t;
        } else {
          bfr[ni] = *(const short8*)&lds_b[(wn*WN + ni*16 + lr)*STRB + kk*32 + lk];
        }
      }
      #pragma unroll
      for (int mi = 0; mi < MF; ++mi)
        #pragma unroll
        for (int ni = 0; ni < NF; ++ni)
          acc[mi][ni] = __builtin_amdgcn_mfma_f32_16x16x32_bf16(af[mi], bfr[ni], acc[mi][ni], 0, 0, 0);
    }
    __syncthreads();
  }

  // ---- epilogue: C/D layout col=lane&15, row=(lane>>4)*4+reg ----
  const long long cbase = bo*strCo + bi*strCi;
  const int cr0 = (lane >> 4) * 4;
  #pragma unroll
  for (int mi = 0; mi < MF; ++mi) {
    #pragma unroll
    for (int ni = 0; ni < NF; ++ni) {
      int row = bm*BM + wm*WM + mi*16 + cr0;
      int col = bn*BN + wn*WN + ni*16 + lr;
      float badd = DO_BIAS ? bias[col] : 0.f;
      #pragma unroll
      for (int r = 0; r < 4; ++r) {
        float x = acc[mi][ni][r];
        if constexpr (DO_SCALE) x *= scale;
        x += badd;
        long long addr = cbase + (long long)(row + r)*ldc + col;
        if constexpr (OUT_BF16) ((unsigned short*)Cv)[addr] = f2bf(x);
        else                    ((float*)Cv)[addr] = x;
      }
    }
  }
}

// softmax over rows of 512 f32, in place; also emit bf16 copy. 1 wave per row.
__global__ __launch_bounds__(256) void softmax_rows(float* __restrict__ sc,
                                                    unsigned short* __restrict__ P) {
  int row = blockIdx.x * 4 + (threadIdx.x >> 6);
  int lane = threadIdx.x & 63;
  float* rp = sc + (long long)row * 512 + lane * 8;
  float4 a = *(const float4*)rp;
  float4 b = *(const float4*)(rp + 4);
  float v[8] = {a.x, a.y, a.z, a.w, b.x, b.y, b.z, b.w};
  float m = v[0];
  #pragma unroll
  for (int i = 1; i < 8; ++i) m = fmaxf(m, v[i]);
  #pragma unroll
  for (int d = 1; d < 64; d <<= 1) m = fmaxf(m, __shfl_xor(m, d, 64));
  float s = 0.f;
  #pragma unroll
  for (int i = 0; i < 8; ++i) { v[i] = __expf(v[i] - m); s += v[i]; }
  #pragma unroll
  for (int d = 1; d < 64; d <<= 1) s += __shfl_xor(s, d, 64);
  float inv = 1.0f / s;
  #pragma unroll
  for (int i = 0; i < 8; ++i) v[i] *= inv;
  float4 oa = {v[0], v[1], v[2], v[3]}, ob = {v[4], v[5], v[6], v[7]};
  *(float4*)rp = oa; *(float4*)(rp + 4) = ob;
  unsigned short* pp = P + (long long)row * 512 + lane * 8;
  ushort4v w0, w1;
  w0.x=f2bf(v[0]); w0.y=f2bf(v[1]); w0.z=f2bf(v[2]); w0.w=f2bf(v[3]);
  w1.x=f2bf(v[4]); w1.y=f2bf(v[5]); w1.z=f2bf(v[6]); w1.w=f2bf(v[7]);
  *(ushort4v*)pp = w0; *(ushort4v*)(pp + 4) = w1;
}

extern "C" void kernel_launch(void* const* d_in, const int* in_sizes, int n_in,
                              void* d_out, int out_size, void* d_ws, size_t ws_size,
                              hipStream_t stream) {
  const float* x       = (const float*)d_in[0];   // (32,512,1024)
  const float* routers = (const float*)d_in[1];   // (8,64,256)
  const float* wkv     = (const float*)d_in[2];   // (2048,1024)
  const float* projw   = (const float*)d_in[3];   // (1024,2048)
  const float* pbias   = (const float*)d_in[4];   // (1024,)

  char* ws = (char*)d_ws;
  unsigned short* wkv_b     = (unsigned short*)(ws);                 //  4,194,304 B
  unsigned short* projw_b   = (unsigned short*)(ws +   4194304);     //  4,194,304 B
  unsigned short* routers_b = (unsigned short*)(ws +   8388608);     //    262,144 B
  unsigned short* kv_b      = (unsigned short*)(ws +   8650752);     // 67,108,864 B  (16384 x 2048)
  unsigned short* P_b       = (unsigned short*)(ws +  75759616);     // 16,777,216 B  (bh x 64 x 512)
  unsigned short* ao_b      = (unsigned short*)(ws +  92536832);     //  8,388,608 B  (2048 x 2048)
  // total ws use: 100,925,440 B

  float* out0  = (float*)d_out;            // (32,64,1024)
  float* attnw = out0 + 2097152;           // (32,8,64,512) — used for f32 scores, softmaxed in place

  cast_f32_bf16<<<2048, 256, 0, stream>>>(wkv,     wkv_b,     524288);
  cast_f32_bf16<<<2048, 256, 0, stream>>>(projw,   projw_b,   524288);
  cast_f32_bf16<<<128,  256, 0, stream>>>(routers, routers_b, 32768);

  // kv = x @ wkv^T : M=16384 N=2048 K=1024, A f32 (converted in staging), out bf16
  gemm_bt<128,128,64,64,64,false,true,true,false,false><<<dim3(2048,1), 256, 0, stream>>>(
      x, wkv_b, kv_b, nullptr, 1024, 1024, 2048, 1024, 16,
      0,0, 0,0, 0,0, 1, 1.0f);

  // S[bh] = routers[h] @ kv[b,h]^T * 1/16 : M=64 N=512 K=256, batch=256, out f32 -> attnw
  gemm_bt<64,128,64,64,32,false,false,false,true,false><<<dim3(4,256), 256, 0, stream>>>(
      routers_b, kv_b, attnw, nullptr, 256, 2048, 512, 256, 4,
      0, 16384, 1048576, 256, 262144, 32768, 8, 0.0625f);

  softmax_rows<<<4096, 256, 0, stream>>>(attnw, P_b);

  // AO[bh] = P[bh] @ kv[b,h] : M=64 N=256 K=512, TRANS_B, out bf16 -> ao_b (b*64+r, h*256+d)
  gemm_bt<64,128,64,64,32,true,false,true,false,false><<<dim3(2,256), 256, 0, stream>>>(
      P_b, kv_b, ao_b, nullptr, 512, 2048, 2048, 512, 2,
      262144, 32768, 1048576, 256, 131072, 256, 8, 1.0f);

  // out = AO @ projw^T + bias : M=2048 N=1024 K=2048, out f32
  gemm_bt<64,128,64,64,32,false,false,false,false,true><<<dim3(256,1), 256, 0, stream>>>(
      ao_b, projw_b, out0, pbias, 2048, 2048, 1024, 2048, 8,
      0,0, 0,0, 0,0, 1, 1.0f);
}